// Round 2
// baseline (555.346 us; speedup 1.0000x reference)
//
#include <hip/hip_runtime.h>
#include <cstdint>

// Problem constants (MultiHeadGraphAttentionLayer_86638080295672)
#define B_    8
#define N_    2048
#define FIN_  256
#define H_    4
#define D_    64
#define NEG_SLOPE 0.2f

// gfx950 MFMA fragment types (v8bf16 inputs, v4f32 acc)
typedef __bf16  bf16x8 __attribute__((ext_vector_type(8)));
typedef uint16_t u16x8 __attribute__((ext_vector_type(8)));
typedef float   fx4    __attribute__((ext_vector_type(4)));

static __device__ __forceinline__ float bf2f(uint16_t u) {
    union { uint32_t u; float f; } c; c.u = ((uint32_t)u) << 16; return c.f;
}
static __device__ __forceinline__ uint16_t f2bf(float f) {
    union { float f; uint32_t u; } c; c.f = f;
    return (uint16_t)((c.u + 0x7fffu + ((c.u >> 16) & 1u)) >> 16);  // RNE
}
static __device__ __forceinline__ bf16x8 ldbf8(const uint16_t* p) {
    return *(const bf16x8*)p;   // 16B load; all call sites 16B-aligned
}
static __device__ __forceinline__ bf16x8 asbf(u16x8 v) {
    union { u16x8 u; bf16x8 b; } c; c.u = v; return c.b;
}
// split 8 contiguous fp32 into hi/lo bf16 fragments
static __device__ __forceinline__ void split8(const float* p, bf16x8& hi, bf16x8& lo) {
    u16x8 h, l;
    #pragma unroll
    for (int j = 0; j < 8; ++j) {
        const float f  = p[j];
        const uint16_t hb = f2bf(f);
        h[j] = hb;
        l[j] = f2bf(f - bf2f(hb));
    }
    hi = asbf(h); lo = asbf(l);
}

// ---------------------------------------------------------------------------
// Kernel 0: Wt_hi/Wt_lo[h][d][f] = bf16 split of W[h][f][d] (fp32 input)
// ---------------------------------------------------------------------------
__global__ void wt_kernel(const float* __restrict__ W,
                          uint16_t* __restrict__ Wt_hi, uint16_t* __restrict__ Wt_lo) {
    const int hd = blockIdx.x;       // head
    const int f  = threadIdx.x;      // 0..255
    const float*    Wh = W + (size_t)hd * FIN_ * D_;
    uint16_t* Whi = Wt_hi + (size_t)hd * D_ * FIN_;
    uint16_t* Wlo = Wt_lo + (size_t)hd * D_ * FIN_;
    for (int d = 0; d < D_; ++d) {
        const float v = Wh[(size_t)f * D_ + d];
        const uint16_t hb = f2bf(v);
        Whi[d * FIN_ + f] = hb;                    // coalesced over f
        Wlo[d * FIN_ + f] = f2bf(v - bf2f(hb));
    }
}

// ---------------------------------------------------------------------------
// Kernel 1: P = h @ W (fp32 via bf16 hi/lo, 3-product). Writes P_hi, P_lo
// [BH][N][D] and Pt_hi [BH][D][N].
// ---------------------------------------------------------------------------
__global__ __launch_bounds__(256) void proj_kernel(
    const float*    __restrict__ hin,    // [B][N][FIN] fp32
    const uint16_t* __restrict__ Wt_hi,  // [H][D][FIN] bf16
    const uint16_t* __restrict__ Wt_lo,
    uint16_t* __restrict__ P_hi,         // [BH][N][D]
    uint16_t* __restrict__ P_lo,
    uint16_t* __restrict__ Pt_hi)        // [BH][D][N]
{
    const int lane = threadIdx.x & 63;
    const int wave = threadIdx.x >> 6;
    const int quad = lane >> 4;
    const int l15  = lane & 15;

    const int bh = blockIdx.y;          // b*H + h
    const int b  = bh >> 2;             // H_ == 4
    const int hd = bh & 3;
    const int n0 = blockIdx.x * 64 + wave * 16;

    const float* arow = hin + ((size_t)b * N_ + n0 + l15) * FIN_ + quad * 8;
    const uint16_t* whi = Wt_hi + (size_t)hd * D_ * FIN_;
    const uint16_t* wlo = Wt_lo + (size_t)hd * D_ * FIN_;

    fx4 acc[4];
    #pragma unroll
    for (int t = 0; t < 4; ++t) acc[t] = (fx4)(0.0f);

    #pragma unroll
    for (int k0 = 0; k0 < FIN_; k0 += 32) {
        bf16x8 ahi, alo;
        split8(arow + k0, ahi, alo);    // A[m=l15][k=quad*8+j]
        #pragma unroll
        for (int t = 0; t < 4; ++t) {
            const size_t off = (size_t)(t * 16 + l15) * FIN_ + k0 + quad * 8;
            const bf16x8 bhi = ldbf8(whi + off);   // B[k=f][n=d]
            const bf16x8 blo = ldbf8(wlo + off);
            acc[t] = __builtin_amdgcn_mfma_f32_16x16x32_bf16(ahi, bhi, acc[t], 0, 0, 0);
            acc[t] = __builtin_amdgcn_mfma_f32_16x16x32_bf16(alo, bhi, acc[t], 0, 0, 0);
            acc[t] = __builtin_amdgcn_mfma_f32_16x16x32_bf16(ahi, blo, acc[t], 0, 0, 0);
        }
    }

    // C/D: row(n) = quad*4+r, col(d) = t*16+l15
    uint16_t* Phb  = P_hi  + (size_t)bh * N_ * D_;
    uint16_t* Plb  = P_lo  + (size_t)bh * N_ * D_;
    uint16_t* Ptb  = Pt_hi + (size_t)bh * D_ * N_;
    #pragma unroll
    for (int t = 0; t < 4; ++t) {
        const int d = t * 16 + l15;
        #pragma unroll
        for (int r = 0; r < 4; ++r) {
            const int n = n0 + quad * 4 + r;
            const float v = acc[t][r];
            const uint16_t hb = f2bf(v);
            Phb[(size_t)n * D_ + d] = hb;
            Plb[(size_t)n * D_ + d] = f2bf(v - bf2f(hb));
            Ptb[(size_t)d * N_ + n] = hb;
        }
    }
}

// ---------------------------------------------------------------------------
// Kernel 2: flash attention per (b,h). Q=K=V=P. leakyrelu before softmax.
// Scores use hi/lo 3-product (fp32-accurate); PV uses bf16 probs x P_hi.
// ---------------------------------------------------------------------------
__global__ __launch_bounds__(256) void attn_kernel(
    const uint16_t* __restrict__ P_hi,   // [BH][N][D]
    const uint16_t* __restrict__ P_lo,
    const uint16_t* __restrict__ Pt_hi,  // [BH][D][N]
    const float*    __restrict__ hin,    // [B][N][FIN] fp32 residual
    float*          __restrict__ out)    // [B][N][FIN] fp32
{
    // wave-private P-tile for C-layout -> A-layout transform (+pad to 72)
    __shared__ __align__(16) uint16_t plds[4][16][72];

    const int lane = threadIdx.x & 63;
    const int wave = threadIdx.x >> 6;
    const int quad = lane >> 4;
    const int l15  = lane & 15;

    const int bh = blockIdx.y;
    const int b  = bh >> 2;
    const int hd = bh & 3;
    const int n0 = blockIdx.x * 64 + wave * 16;

    const uint16_t* Ph  = P_hi  + (size_t)bh * N_ * D_;
    const uint16_t* Pl  = P_lo  + (size_t)bh * N_ * D_;
    const uint16_t* Ptb = Pt_hi + (size_t)bh * D_ * N_;

    // Q fragments (k = d, two 32-chunks), hi and lo
    const size_t qoff = (size_t)(n0 + l15) * D_ + quad * 8;
    const bf16x8 qh0 = ldbf8(Ph + qoff), qh1 = ldbf8(Ph + qoff + 32);
    const bf16x8 ql0 = ldbf8(Pl + qoff), ql1 = ldbf8(Pl + qoff + 32);

    float m_i[4], l_i[4];
    fx4 oacc[4];
    #pragma unroll
    for (int r = 0; r < 4; ++r) { m_i[r] = -1e30f; l_i[r] = 0.0f; }
    #pragma unroll
    for (int t = 0; t < 4; ++t) oacc[t] = (fx4)(0.0f);

    for (int key0 = 0; key0 < N_; key0 += 64) {
        // ---- S = Q K^T (16 rows x 64 keys); B-frag from K rows (contiguous d)
        fx4 s[4];
        #pragma unroll
        for (int t = 0; t < 4; ++t) s[t] = (fx4)(0.0f);
        #pragma unroll
        for (int t = 0; t < 4; ++t) {
            const size_t koff = (size_t)(key0 + t * 16 + l15) * D_ + quad * 8;
            const bf16x8 kh0 = ldbf8(Ph + koff), kh1 = ldbf8(Ph + koff + 32);
            const bf16x8 kl0 = ldbf8(Pl + koff), kl1 = ldbf8(Pl + koff + 32);
            s[t] = __builtin_amdgcn_mfma_f32_16x16x32_bf16(qh0, kh0, s[t], 0, 0, 0);
            s[t] = __builtin_amdgcn_mfma_f32_16x16x32_bf16(qh1, kh1, s[t], 0, 0, 0);
            s[t] = __builtin_amdgcn_mfma_f32_16x16x32_bf16(ql0, kh0, s[t], 0, 0, 0);
            s[t] = __builtin_amdgcn_mfma_f32_16x16x32_bf16(ql1, kh1, s[t], 0, 0, 0);
            s[t] = __builtin_amdgcn_mfma_f32_16x16x32_bf16(qh0, kl0, s[t], 0, 0, 0);
            s[t] = __builtin_amdgcn_mfma_f32_16x16x32_bf16(qh1, kl1, s[t], 0, 0, 0);
        }

        // ---- leakyrelu
        float p[4][4];
        #pragma unroll
        for (int t = 0; t < 4; ++t)
            #pragma unroll
            for (int r = 0; r < 4; ++r) {
                const float v = s[t][r];
                p[t][r] = v > 0.0f ? v : NEG_SLOPE * v;
            }

        // ---- online softmax (row = quad*4+r; keys over 16 lanes x 4 tiles)
        #pragma unroll
        for (int r = 0; r < 4; ++r) {
            float mx = fmaxf(fmaxf(p[0][r], p[1][r]), fmaxf(p[2][r], p[3][r]));
            #pragma unroll
            for (int m = 1; m < 16; m <<= 1) mx = fmaxf(mx, __shfl_xor(mx, m));
            const float mnew  = fmaxf(m_i[r], mx);
            const float alpha = __expf(m_i[r] - mnew);
            float rs = 0.0f;
            #pragma unroll
            for (int t = 0; t < 4; ++t) { p[t][r] = __expf(p[t][r] - mnew); rs += p[t][r]; }
            #pragma unroll
            for (int m = 1; m < 16; m <<= 1) rs += __shfl_xor(rs, m);
            l_i[r] = l_i[r] * alpha + rs;
            m_i[r] = mnew;
            #pragma unroll
            for (int t = 0; t < 4; ++t) oacc[t][r] *= alpha;
        }

        // ---- C-layout -> A-layout via wave-private LDS (lockstep wave, no barrier)
        #pragma unroll
        for (int t = 0; t < 4; ++t)
            #pragma unroll
            for (int r = 0; r < 4; ++r)
                plds[wave][quad * 4 + r][t * 16 + l15] = f2bf(p[t][r]);

        const bf16x8 a0 = ldbf8(&plds[wave][l15][quad * 8]);
        const bf16x8 a1 = ldbf8(&plds[wave][l15][32 + quad * 8]);

        // ---- O += P_tile * V ; V-frag B[k=key][n=d] = Pt_hi[d][key]
        #pragma unroll
        for (int dt = 0; dt < 4; ++dt) {
            const uint16_t* vrow = Ptb + (size_t)(dt * 16 + l15) * N_ + key0 + quad * 8;
            oacc[dt] = __builtin_amdgcn_mfma_f32_16x16x32_bf16(a0, ldbf8(vrow),      oacc[dt], 0, 0, 0);
            oacc[dt] = __builtin_amdgcn_mfma_f32_16x16x32_bf16(a1, ldbf8(vrow + 32), oacc[dt], 0, 0, 0);
        }
    }

    // ---- epilogue: O/l + residual (fp32), fp32 store
    float inv[4];
    #pragma unroll
    for (int r = 0; r < 4; ++r) inv[r] = 1.0f / l_i[r];
    #pragma unroll
    for (int dt = 0; dt < 4; ++dt) {
        const int col = hd * D_ + dt * 16 + l15;
        #pragma unroll
        for (int r = 0; r < 4; ++r) {
            const int n = n0 + quad * 4 + r;
            const size_t idx = ((size_t)b * N_ + n) * FIN_ + col;
            out[idx] = oacc[dt][r] * inv[r] + hin[idx];
        }
    }
}

// ---------------------------------------------------------------------------
extern "C" void kernel_launch(void* const* d_in, const int* in_sizes, int n_in,
                              void* d_out, int out_size, void* d_ws, size_t ws_size,
                              hipStream_t stream) {
    const float* hin = (const float*)d_in[0];   // h   [8,2048,256] fp32
    // d_in[1] = adj — dead input (never used by the reference math)
    const float* W   = (const float*)d_in[2];   // W   [4,256,64]   fp32
    float* out = (float*)d_out;                 // [8,2048,256] fp32

    // workspace (bf16 elements): Wt_hi | Wt_lo | P_hi | P_lo | Pt_hi  (~24.3 MB)
    uint16_t* Wt_hi = (uint16_t*)d_ws;
    uint16_t* Wt_lo = Wt_hi + (size_t)H_ * D_ * FIN_;
    uint16_t* P_hi  = Wt_lo + (size_t)H_ * D_ * FIN_;
    uint16_t* P_lo  = P_hi  + (size_t)B_ * H_ * N_ * D_;
    uint16_t* Pt_hi = P_lo  + (size_t)B_ * H_ * N_ * D_;

    hipLaunchKernelGGL(wt_kernel,   dim3(H_),           dim3(FIN_), 0, stream, W, Wt_hi, Wt_lo);
    hipLaunchKernelGGL(proj_kernel, dim3(N_/64, B_*H_), dim3(256),  0, stream,
                       hin, Wt_hi, Wt_lo, P_hi, P_lo, Pt_hi);
    hipLaunchKernelGGL(attn_kernel, dim3(N_/64, B_*H_), dim3(256),  0, stream,
                       P_hi, P_lo, Pt_hi, hin, out);
}

// Round 3
// 326.637 us; speedup vs baseline: 1.7002x; 1.7002x over previous
//
#include <hip/hip_runtime.h>
#include <cstdint>

// Problem constants (MultiHeadGraphAttentionLayer_86638080295672)
#define B_    8
#define N_    2048
#define FIN_  256
#define H_    4
#define D_    64
#define NEG_SLOPE 0.2f

typedef __bf16   bf16x8 __attribute__((ext_vector_type(8)));
typedef uint16_t u16x8  __attribute__((ext_vector_type(8)));
typedef float    fx4    __attribute__((ext_vector_type(4)));

static __device__ __forceinline__ float bf2f(uint16_t u) {
    union { uint32_t u; float f; } c; c.u = ((uint32_t)u) << 16; return c.f;
}
static __device__ __forceinline__ uint16_t f2bf(float f) {
    union { float f; uint32_t u; } c; c.f = f;
    return (uint16_t)((c.u + 0x7fffu + ((c.u >> 16) & 1u)) >> 16);  // RNE
}
static __device__ __forceinline__ bf16x8 ldbf8(const uint16_t* p) {
    return *(const bf16x8*)p;   // 16B load; all call sites 16B-aligned
}
static __device__ __forceinline__ bf16x8 asbf(u16x8 v) {
    union { u16x8 u; bf16x8 b; } c; c.u = v; return c.b;
}
static __device__ __forceinline__ void split8(const float* p, bf16x8& hi, bf16x8& lo) {
    const float4 x0 = *(const float4*)p;
    const float4 x1 = *(const float4*)(p + 4);
    const float f[8] = {x0.x, x0.y, x0.z, x0.w, x1.x, x1.y, x1.z, x1.w};
    u16x8 h, l;
    #pragma unroll
    for (int j = 0; j < 8; ++j) {
        const uint16_t hb = f2bf(f[j]);
        h[j] = hb;
        l[j] = f2bf(f[j] - bf2f(hb));
    }
    hi = asbf(h); lo = asbf(l);
}

// ---- DPP rotate-butterfly reductions over 16-lane rows (pure VALU) --------
template <int CTRL>
static __device__ __forceinline__ float dpp_mov(float x) {
    int i = __builtin_bit_cast(int, x);
    i = __builtin_amdgcn_update_dpp(i, i, CTRL, 0xF, 0xF, false);
    return __builtin_bit_cast(float, i);
}
static __device__ __forceinline__ float rowmax16(float x) {
    x = fmaxf(x, dpp_mov<0x128>(x));  // row_ror:8
    x = fmaxf(x, dpp_mov<0x124>(x));  // row_ror:4
    x = fmaxf(x, dpp_mov<0x122>(x));  // row_ror:2
    x = fmaxf(x, dpp_mov<0x121>(x));  // row_ror:1
    return x;                         // all 16 lanes hold the max
}
static __device__ __forceinline__ float rowsum16(float x) {
    x += dpp_mov<0x128>(x);
    x += dpp_mov<0x124>(x);
    x += dpp_mov<0x122>(x);
    x += dpp_mov<0x121>(x);
    return x;                         // all 16 lanes hold the sum
}

// ---------------------------------------------------------------------------
// Kernel 0 (prep): Wt_hi/Wt_lo[h][d][f] = bf16 hi/lo split of W[h][f][d]
// ---------------------------------------------------------------------------
__global__ void prep_kernel(const float* __restrict__ W,
                            uint16_t* __restrict__ Wt_hi,
                            uint16_t* __restrict__ Wt_lo) {
    const int h  = blockIdx.x >> 4;
    const int d4 = blockIdx.x & 15;
    const int f  = threadIdx.x;
    const float4 w = *(const float4*)(W + (((size_t)h * FIN_ + f) * D_ + d4 * 4));
    const float vv[4] = {w.x, w.y, w.z, w.w};
    #pragma unroll
    for (int j = 0; j < 4; ++j) {
        const int d = d4 * 4 + j;
        const uint16_t hb = f2bf(vv[j]);
        Wt_hi[((size_t)h * D_ + d) * FIN_ + f] = hb;
        Wt_lo[((size_t)h * D_ + d) * FIN_ + f] = f2bf(vv[j] - bf2f(hb));
    }
}

// ---------------------------------------------------------------------------
// Kernel 1: P = h @ W (hi/lo 3-product MFMA). 2 heads per block.
// Writes P_hi,P_lo [BH][N][D] (vectorized via LDS) and Pt_hi [BH][D][N].
// ---------------------------------------------------------------------------
__global__ __launch_bounds__(256, 2) void proj_kernel(
    const float*    __restrict__ hin,
    const uint16_t* __restrict__ Wt_hi,
    const uint16_t* __restrict__ Wt_lo,
    uint16_t* __restrict__ P_hi,
    uint16_t* __restrict__ P_lo,
    uint16_t* __restrict__ Pt_hi)
{
    __shared__ __align__(16) uint16_t plds[4][16][72];

    const int lane = threadIdx.x & 63, wave = threadIdx.x >> 6;
    const int quad = lane >> 4, l15 = lane & 15;

    const int b  = blockIdx.y;
    const int h0 = blockIdx.z * 2;
    const int n0 = blockIdx.x * 64 + wave * 16;

    const float* arow = hin + ((size_t)b * N_ + n0 + l15) * FIN_ + quad * 8;

    fx4 acc[2][4];
    #pragma unroll
    for (int hh = 0; hh < 2; ++hh)
        #pragma unroll
        for (int t = 0; t < 4; ++t) acc[hh][t] = (fx4)(0.0f);

    #pragma unroll
    for (int k0 = 0; k0 < FIN_; k0 += 32) {
        bf16x8 ahi, alo;
        split8(arow + k0, ahi, alo);
        #pragma unroll
        for (int hh = 0; hh < 2; ++hh) {
            const uint16_t* whi = Wt_hi + (size_t)(h0 + hh) * D_ * FIN_;
            const uint16_t* wlo = Wt_lo + (size_t)(h0 + hh) * D_ * FIN_;
            #pragma unroll
            for (int t = 0; t < 4; ++t) {
                const size_t off = (size_t)(t * 16 + l15) * FIN_ + k0 + quad * 8;
                const bf16x8 bhi = ldbf8(whi + off);
                const bf16x8 blo = ldbf8(wlo + off);
                acc[hh][t] = __builtin_amdgcn_mfma_f32_16x16x32_bf16(ahi, bhi, acc[hh][t], 0, 0, 0);
                acc[hh][t] = __builtin_amdgcn_mfma_f32_16x16x32_bf16(alo, bhi, acc[hh][t], 0, 0, 0);
                acc[hh][t] = __builtin_amdgcn_mfma_f32_16x16x32_bf16(ahi, blo, acc[hh][t], 0, 0, 0);
            }
        }
    }

    #pragma unroll
    for (int hh = 0; hh < 2; ++hh) {
        const int bh = b * H_ + h0 + hh;
        // ---- hi pass: C-layout -> plds (wave-private, lockstep)
        #pragma unroll
        for (int t = 0; t < 4; ++t)
            #pragma unroll
            for (int r = 0; r < 4; ++r)
                plds[wave][quad * 4 + r][t * 16 + l15] = f2bf(acc[hh][t][r]);

        // rows -> P_hi (b128 stores)
        {
            const uint16_t* base = &plds[wave][l15][0];
            const int4 r0 = *(const int4*)(base + quad * 8);
            const int4 r1 = *(const int4*)(base + quad * 8 + 32);
            uint16_t* pg = P_hi + ((size_t)bh * N_ + n0 + l15) * D_;
            *(int4*)(pg + quad * 8)      = r0;
            *(int4*)(pg + quad * 8 + 32) = r1;
        }
        // cols -> Pt_hi (transpose; 2 b128 stores per lane, lane = d)
        {
            uint32_t u[8];
            #pragma unroll
            for (int j = 0; j < 8; ++j) {
                const uint16_t e0 = plds[wave][2 * j][lane];
                const uint16_t e1 = plds[wave][2 * j + 1][lane];
                u[j] = (uint32_t)e0 | ((uint32_t)e1 << 16);
            }
            uint16_t* pt = Pt_hi + ((size_t)bh * D_ + lane) * N_ + n0;
            int4 s0, s1;
            s0.x = u[0]; s0.y = u[1]; s0.z = u[2]; s0.w = u[3];
            s1.x = u[4]; s1.y = u[5]; s1.z = u[6]; s1.w = u[7];
            *(int4*)pt       = s0;
            *(int4*)(pt + 8) = s1;
        }
        // ---- lo pass
        #pragma unroll
        for (int t = 0; t < 4; ++t)
            #pragma unroll
            for (int r = 0; r < 4; ++r) {
                const float v = acc[hh][t][r];
                plds[wave][quad * 4 + r][t * 16 + l15] = f2bf(v - bf2f(f2bf(v)));
            }
        {
            const uint16_t* base = &plds[wave][l15][0];
            const int4 r0 = *(const int4*)(base + quad * 8);
            const int4 r1 = *(const int4*)(base + quad * 8 + 32);
            uint16_t* pg = P_lo + ((size_t)bh * N_ + n0 + l15) * D_;
            *(int4*)(pg + quad * 8)      = r0;
            *(int4*)(pg + quad * 8 + 32) = r1;
        }
    }
}

// ---------------------------------------------------------------------------
// Kernel 2: flash attention. Block = 4 waves x 32 Q-rows = 128 rows.
// K_hi/K_lo/V staged in LDS (xor-swizzled), register-prefetch pipeline.
// ---------------------------------------------------------------------------
__global__ __launch_bounds__(256, 2) void attn_kernel(
    const uint16_t* __restrict__ P_hi,
    const uint16_t* __restrict__ P_lo,
    const uint16_t* __restrict__ Pt_hi,
    const float*    __restrict__ hin,
    float*          __restrict__ out)
{
    __shared__ __align__(16) uint16_t sKhi[64 * 64];
    __shared__ __align__(16) uint16_t sKlo[64 * 64];
    __shared__ __align__(16) uint16_t sV  [64 * 64];
    __shared__ __align__(16) uint16_t plds[4][32][72];

    const int tid  = threadIdx.x;
    const int lane = tid & 63, wave = tid >> 6;
    const int quad = lane >> 4, l15 = lane & 15;

    const int bh = blockIdx.y, b = bh >> 2, hd = bh & 3;
    const int n0 = blockIdx.x * 128 + wave * 32;

    const uint16_t* Ph = P_hi  + (size_t)bh * N_ * D_;
    const uint16_t* Pl = P_lo  + (size_t)bh * N_ * D_;
    const uint16_t* Pt = Pt_hi + (size_t)bh * D_ * N_;

    // Q fragments (2 m-tiles, hi+lo)
    bf16x8 qh[2][2], ql[2][2];
    #pragma unroll
    for (int mt = 0; mt < 2; ++mt) {
        const size_t off = (size_t)(n0 + mt * 16 + l15) * D_ + quad * 8;
        qh[mt][0] = ldbf8(Ph + off); qh[mt][1] = ldbf8(Ph + off + 32);
        ql[mt][0] = ldbf8(Pl + off); ql[mt][1] = ldbf8(Pl + off + 32);
    }

    // staging slots: thread covers slots tid and tid+256 of each array.
    // LDS[row][c] = G[row][c ^ (row&7)]  (swizzle folded into global address)
    const int i0 = tid, i1 = tid + 256;
    const int r0s = i0 >> 3, c0s = i0 & 7;
    const int r1s = i1 >> 3, c1s = i1 & 7;
    const uint16_t* gKh0 = Ph + (size_t)r0s * D_ + (c0s ^ (r0s & 7)) * 8;
    const uint16_t* gKh1 = Ph + (size_t)r1s * D_ + (c1s ^ (r1s & 7)) * 8;
    const uint16_t* gKl0 = Pl + (size_t)r0s * D_ + (c0s ^ (r0s & 7)) * 8;
    const uint16_t* gKl1 = Pl + (size_t)r1s * D_ + (c1s ^ (r1s & 7)) * 8;
    const uint16_t* gV0  = Pt + (size_t)r0s * N_ + (c0s ^ (r0s & 7)) * 8;
    const uint16_t* gV1  = Pt + (size_t)r1s * N_ + (c1s ^ (r1s & 7)) * 8;

    // prologue: loads for tile 0
    int4 rKh0 = *(const int4*)gKh0, rKh1 = *(const int4*)gKh1;
    int4 rKl0 = *(const int4*)gKl0, rKl1 = *(const int4*)gKl1;
    int4 rV0  = *(const int4*)gV0,  rV1  = *(const int4*)gV1;

    float m_i[2][4], l_i[2][4];
    fx4 oacc[2][4];
    #pragma unroll
    for (int mt = 0; mt < 2; ++mt) {
        #pragma unroll
        for (int r = 0; r < 4; ++r) { m_i[mt][r] = -1e30f; l_i[mt][r] = 0.0f; }
        #pragma unroll
        for (int dt = 0; dt < 4; ++dt) oacc[mt][dt] = (fx4)(0.0f);
    }

    for (int it = 0; it < N_ / 64; ++it) {
        __syncthreads();   // all waves done reading previous tile
        ((int4*)sKhi)[i0] = rKh0; ((int4*)sKhi)[i1] = rKh1;
        ((int4*)sKlo)[i0] = rKl0; ((int4*)sKlo)[i1] = rKl1;
        ((int4*)sV)[i0]   = rV0;  ((int4*)sV)[i1]   = rV1;
        // prefetch next tile into regs (consumed next iter -> latency hidden)
        const int knx = (it < N_ / 64 - 1) ? (it + 1) * 64 : 0;
        rKh0 = *(const int4*)(gKh0 + (size_t)knx * D_);
        rKh1 = *(const int4*)(gKh1 + (size_t)knx * D_);
        rKl0 = *(const int4*)(gKl0 + (size_t)knx * D_);
        rKl1 = *(const int4*)(gKl1 + (size_t)knx * D_);
        rV0  = *(const int4*)(gV0 + knx);
        rV1  = *(const int4*)(gV1 + knx);
        __syncthreads();   // staged tile visible

        // ---- S = Q K^T : 2 m-tiles x 64 keys
        fx4 s[2][4];
        #pragma unroll
        for (int mt = 0; mt < 2; ++mt)
            #pragma unroll
            for (int t = 0; t < 4; ++t) s[mt][t] = (fx4)(0.0f);

        const int cc = quad ^ (l15 & 7);
        #pragma unroll
        for (int t = 0; t < 4; ++t) {
            const int key = t * 16 + l15;
            const uint16_t* kb  = sKhi + key * 64;
            const uint16_t* klb = sKlo + key * 64;
            const bf16x8 kh0 = ldbf8(kb + cc * 8);
            const bf16x8 kh1 = ldbf8(kb + (cc ^ 4) * 8);
            const bf16x8 kl0 = ldbf8(klb + cc * 8);
            const bf16x8 kl1 = ldbf8(klb + (cc ^ 4) * 8);
            #pragma unroll
            for (int mt = 0; mt < 2; ++mt) {
                s[mt][t] = __builtin_amdgcn_mfma_f32_16x16x32_bf16(qh[mt][0], kh0, s[mt][t], 0, 0, 0);
                s[mt][t] = __builtin_amdgcn_mfma_f32_16x16x32_bf16(qh[mt][1], kh1, s[mt][t], 0, 0, 0);
                s[mt][t] = __builtin_amdgcn_mfma_f32_16x16x32_bf16(ql[mt][0], kh0, s[mt][t], 0, 0, 0);
                s[mt][t] = __builtin_amdgcn_mfma_f32_16x16x32_bf16(ql[mt][1], kh1, s[mt][t], 0, 0, 0);
                s[mt][t] = __builtin_amdgcn_mfma_f32_16x16x32_bf16(qh[mt][0], kl0, s[mt][t], 0, 0, 0);
                s[mt][t] = __builtin_amdgcn_mfma_f32_16x16x32_bf16(qh[mt][1], kl1, s[mt][t], 0, 0, 0);
            }
        }

        // ---- leakyrelu + online softmax (DPP reductions, zero LDS traffic)
        float p[2][4][4];
        #pragma unroll
        for (int mt = 0; mt < 2; ++mt)
            #pragma unroll
            for (int r = 0; r < 4; ++r) {
                float pm[4];
                #pragma unroll
                for (int t = 0; t < 4; ++t) {
                    const float v = s[mt][t][r];
                    pm[t] = v > 0.0f ? v : NEG_SLOPE * v;
                }
                float mx = fmaxf(fmaxf(pm[0], pm[1]), fmaxf(pm[2], pm[3]));
                mx = rowmax16(mx);
                const float mnew  = fmaxf(m_i[mt][r], mx);
                const float alpha = __expf(m_i[mt][r] - mnew);
                float rs = 0.0f;
                #pragma unroll
                for (int t = 0; t < 4; ++t) {
                    const float e = __expf(pm[t] - mnew);
                    p[mt][t][r] = e; rs += e;
                }
                rs = rowsum16(rs);
                l_i[mt][r] = l_i[mt][r] * alpha + rs;
                m_i[mt][r] = mnew;
                #pragma unroll
                for (int dt = 0; dt < 4; ++dt) oacc[mt][dt][r] *= alpha;
            }

        // ---- C-layout -> A-layout via wave-private plds (no barrier)
        #pragma unroll
        for (int mt = 0; mt < 2; ++mt)
            #pragma unroll
            for (int t = 0; t < 4; ++t)
                #pragma unroll
                for (int r = 0; r < 4; ++r)
                    plds[wave][mt * 16 + quad * 4 + r][t * 16 + l15] = f2bf(p[mt][t][r]);

        bf16x8 a[2][2];
        #pragma unroll
        for (int mt = 0; mt < 2; ++mt) {
            const uint16_t* pb = &plds[wave][mt * 16 + l15][0];
            a[mt][0] = ldbf8(pb + quad * 8);
            a[mt][1] = ldbf8(pb + quad * 8 + 32);
        }

        // ---- O += P_tile * V
        #pragma unroll
        for (int dt = 0; dt < 4; ++dt) {
            const int d = dt * 16 + l15;
            const uint16_t* vb = sV + d * 64;
            const bf16x8 v0 = ldbf8(vb + cc * 8);
            const bf16x8 v1 = ldbf8(vb + (cc ^ 4) * 8);
            #pragma unroll
            for (int mt = 0; mt < 2; ++mt) {
                oacc[mt][dt] = __builtin_amdgcn_mfma_f32_16x16x32_bf16(a[mt][0], v0, oacc[mt][dt], 0, 0, 0);
                oacc[mt][dt] = __builtin_amdgcn_mfma_f32_16x16x32_bf16(a[mt][1], v1, oacc[mt][dt], 0, 0, 0);
            }
        }
    }

    // ---- epilogue: O/l + residual, fp32 store
    #pragma unroll
    for (int mt = 0; mt < 2; ++mt) {
        float inv[4];
        #pragma unroll
        for (int r = 0; r < 4; ++r) inv[r] = 1.0f / l_i[mt][r];
        #pragma unroll
        for (int dt = 0; dt < 4; ++dt) {
            const int col = hd * D_ + dt * 16 + l15;
            #pragma unroll
            for (int r = 0; r < 4; ++r) {
                const int n = n0 + mt * 16 + quad * 4 + r;
                const size_t idx = ((size_t)b * N_ + n) * FIN_ + col;
                out[idx] = oacc[mt][dt][r] * inv[r] + hin[idx];
            }
        }
    }
}

// ---------------------------------------------------------------------------
extern "C" void kernel_launch(void* const* d_in, const int* in_sizes, int n_in,
                              void* d_out, int out_size, void* d_ws, size_t ws_size,
                              hipStream_t stream) {
    const float* hin = (const float*)d_in[0];   // h   [8,2048,256] fp32
    // d_in[1] = adj — dead input
    const float* W   = (const float*)d_in[2];   // W   [4,256,64]   fp32
    float* out = (float*)d_out;

    // workspace (bf16 elems): Wt_hi | Wt_lo | P_hi | P_lo | Pt_hi  (~25.4 MB)
    uint16_t* Wt_hi = (uint16_t*)d_ws;
    uint16_t* Wt_lo = Wt_hi + (size_t)H_ * D_ * FIN_;
    uint16_t* P_hi  = Wt_lo + (size_t)H_ * D_ * FIN_;
    uint16_t* P_lo  = P_hi  + (size_t)B_ * H_ * N_ * D_;
    uint16_t* Pt_hi = P_lo  + (size_t)B_ * H_ * N_ * D_;

    hipLaunchKernelGGL(prep_kernel, dim3(H_ * 16),            dim3(FIN_), 0, stream, W, Wt_hi, Wt_lo);
    hipLaunchKernelGGL(proj_kernel, dim3(N_/64, B_, H_/2),    dim3(256),  0, stream,
                       hin, Wt_hi, Wt_lo, P_hi, P_lo, Pt_hi);
    hipLaunchKernelGGL(attn_kernel, dim3(N_/128, B_*H_),      dim3(256),  0, stream,
                       P_hi, P_lo, Pt_hi, hin, out);
}

// Round 5
// 278.305 us; speedup vs baseline: 1.9955x; 1.1737x over previous
//
#include <hip/hip_runtime.h>
#include <cstdint>

// Problem constants (MultiHeadGraphAttentionLayer_86638080295672)
#define B_    8
#define N_    2048
#define FIN_  256
#define H_    4
#define D_    64
#define NEG_SLOPE 0.2f
#define LOG2E 1.44269504f

typedef __bf16    bf16x8 __attribute__((ext_vector_type(8)));
typedef _Float16  f16x8  __attribute__((ext_vector_type(8)));
typedef __fp16    fp16x2 __attribute__((ext_vector_type(2)));  // cvt_pkrtz return type
typedef uint16_t  u16x8  __attribute__((ext_vector_type(8)));
typedef float     fx4    __attribute__((ext_vector_type(4)));

static __device__ __forceinline__ float bf2f(uint16_t u) {
    union { uint32_t u; float f; } c; c.u = ((uint32_t)u) << 16; return c.f;
}
static __device__ __forceinline__ uint16_t f2bf(float f) {
    union { float f; uint32_t u; } c; c.f = f;
    return (uint16_t)((c.u + 0x7fffu + ((c.u >> 16) & 1u)) >> 16);  // RNE
}
static __device__ __forceinline__ uint16_t f2h(float f) {
    const _Float16 h = (_Float16)f;                 // v_cvt_f16_f32 RNE
    return __builtin_bit_cast(uint16_t, h);
}
static __device__ __forceinline__ bf16x8 ldbf8(const uint16_t* p) {
    return *(const bf16x8*)p;
}
static __device__ __forceinline__ f16x8 ldf8(const uint16_t* p) {
    return *(const f16x8*)p;
}
static __device__ __forceinline__ bf16x8 asbf(u16x8 v) {
    union { u16x8 u; bf16x8 b; } c; c.u = v; return c.b;
}
static __device__ __forceinline__ void split8(const float* p, bf16x8& hi, bf16x8& lo) {
    const float4 x0 = *(const float4*)p;
    const float4 x1 = *(const float4*)(p + 4);
    const float f[8] = {x0.x, x0.y, x0.z, x0.w, x1.x, x1.y, x1.z, x1.w};
    u16x8 h, l;
    #pragma unroll
    for (int j = 0; j < 8; ++j) {
        const uint16_t hb = f2bf(f[j]);
        h[j] = hb;
        l[j] = f2bf(f[j] - bf2f(hb));
    }
    hi = asbf(h); lo = asbf(l);
}
static __device__ __forceinline__ uint32_t pkh2(float a, float b) {
    const fp16x2 h = __builtin_amdgcn_cvt_pkrtz(a, b);  // v_cvt_pkrtz_f16_f32
    return __builtin_bit_cast(uint32_t, h);
}

// ---------------------------------------------------------------------------
// Kernel 0 (prep): Wt_hi/Wt_lo[h][d][f] = bf16 hi/lo split of W[h][f][d]
// ---------------------------------------------------------------------------
__global__ void prep_kernel(const float* __restrict__ W,
                            uint16_t* __restrict__ Wt_hi,
                            uint16_t* __restrict__ Wt_lo) {
    const int h  = blockIdx.x >> 4;
    const int d4 = blockIdx.x & 15;
    const int f  = threadIdx.x;
    const float4 w = *(const float4*)(W + (((size_t)h * FIN_ + f) * D_ + d4 * 4));
    const float vv[4] = {w.x, w.y, w.z, w.w};
    #pragma unroll
    for (int j = 0; j < 4; ++j) {
        const int d = d4 * 4 + j;
        const uint16_t hb = f2bf(vv[j]);
        Wt_hi[((size_t)h * D_ + d) * FIN_ + f] = hb;
        Wt_lo[((size_t)h * D_ + d) * FIN_ + f] = f2bf(vv[j] - bf2f(hb));
    }
}

// ---------------------------------------------------------------------------
// Kernel 1: P = h @ W (hi/lo bf16 3-product MFMA, fp32-accurate).
// Outputs fp16: P_f16 [BH][N][D] and Pt_f16 [BH][D][N].
// ---------------------------------------------------------------------------
__global__ __launch_bounds__(256, 2) void proj_kernel(
    const float*    __restrict__ hin,
    const uint16_t* __restrict__ Wt_hi,
    const uint16_t* __restrict__ Wt_lo,
    uint16_t* __restrict__ P_f16,
    uint16_t* __restrict__ Pt_f16)
{
    __shared__ __align__(16) uint16_t plds[4][16][72];

    const int lane = threadIdx.x & 63, wave = threadIdx.x >> 6;
    const int quad = lane >> 4, l15 = lane & 15;

    const int b  = blockIdx.y;
    const int h0 = blockIdx.z * 2;
    const int n0 = blockIdx.x * 64 + wave * 16;

    const float* arow = hin + ((size_t)b * N_ + n0 + l15) * FIN_ + quad * 8;

    fx4 acc[2][4];
    #pragma unroll
    for (int hh = 0; hh < 2; ++hh)
        #pragma unroll
        for (int t = 0; t < 4; ++t) acc[hh][t] = (fx4)(0.0f);

    #pragma unroll
    for (int k0 = 0; k0 < FIN_; k0 += 32) {
        bf16x8 ahi, alo;
        split8(arow + k0, ahi, alo);
        #pragma unroll
        for (int hh = 0; hh < 2; ++hh) {
            const uint16_t* whi = Wt_hi + (size_t)(h0 + hh) * D_ * FIN_;
            const uint16_t* wlo = Wt_lo + (size_t)(h0 + hh) * D_ * FIN_;
            #pragma unroll
            for (int t = 0; t < 4; ++t) {
                const size_t off = (size_t)(t * 16 + l15) * FIN_ + k0 + quad * 8;
                const bf16x8 bhi = ldbf8(whi + off);
                const bf16x8 blo = ldbf8(wlo + off);
                acc[hh][t] = __builtin_amdgcn_mfma_f32_16x16x32_bf16(ahi, bhi, acc[hh][t], 0, 0, 0);
                acc[hh][t] = __builtin_amdgcn_mfma_f32_16x16x32_bf16(alo, bhi, acc[hh][t], 0, 0, 0);
                acc[hh][t] = __builtin_amdgcn_mfma_f32_16x16x32_bf16(ahi, blo, acc[hh][t], 0, 0, 0);
            }
        }
    }

    #pragma unroll
    for (int hh = 0; hh < 2; ++hh) {
        const int bh = b * H_ + h0 + hh;
        // C-layout -> plds as fp16 (wave-private, lockstep)
        #pragma unroll
        for (int t = 0; t < 4; ++t)
            #pragma unroll
            for (int r = 0; r < 4; ++r)
                plds[wave][quad * 4 + r][t * 16 + l15] = f2h(acc[hh][t][r]);

        // rows -> P_f16 (b128 stores)
        {
            const uint16_t* base = &plds[wave][l15][0];
            const int4 r0 = *(const int4*)(base + quad * 8);
            const int4 r1 = *(const int4*)(base + quad * 8 + 32);
            uint16_t* pg = P_f16 + ((size_t)bh * N_ + n0 + l15) * D_;
            *(int4*)(pg + quad * 8)      = r0;
            *(int4*)(pg + quad * 8 + 32) = r1;
        }
        // cols -> Pt_f16 (transpose; 2 b128 stores per lane, lane = d)
        {
            uint32_t u[8];
            #pragma unroll
            for (int j = 0; j < 8; ++j) {
                const uint16_t e0 = plds[wave][2 * j][lane];
                const uint16_t e1 = plds[wave][2 * j + 1][lane];
                u[j] = (uint32_t)e0 | ((uint32_t)e1 << 16);
            }
            uint16_t* pt = Pt_f16 + ((size_t)bh * D_ + lane) * N_ + n0;
            int4 s0, s1;
            s0.x = u[0]; s0.y = u[1]; s0.z = u[2]; s0.w = u[3];
            s1.x = u[4]; s1.y = u[5]; s1.z = u[6]; s1.w = u[7];
            *(int4*)pt       = s0;
            *(int4*)(pt + 8) = s1;
        }
    }
}

// ---------------------------------------------------------------------------
// Kernel 2: flash attention, S^T formulation. Block = 4 waves x 16 Q-rows.
// s = mfma(K_frag, Q_frag): row=key, col=Q-row -> full score row in 4 lanes.
// O^T = mfma(V_frag, Prob_frag): row=d, col=Q-row.
// Q pre-scaled by log2e so all exps are exp2 (exact softmax reformulation).
// ---------------------------------------------------------------------------
__global__ __launch_bounds__(256, 4) void attn_kernel(
    const uint16_t* __restrict__ P_f16,   // [BH][N][D]
    const uint16_t* __restrict__ Pt_f16,  // [BH][D][N]
    const float*    __restrict__ hin,
    float*          __restrict__ out)
{
    __shared__ __align__(16) uint16_t sK[64 * 64];
    __shared__ __align__(16) uint16_t sV[64 * 64];
    __shared__ __align__(16) uint16_t plds[4][16][72];

    const int tid  = threadIdx.x;
    const int lane = tid & 63, wave = tid >> 6;
    const int quad = lane >> 4, l15 = lane & 15;

    const int bh = blockIdx.y, b = bh >> 2, hd = bh & 3;
    const int n0 = blockIdx.x * 64 + wave * 16;

    const uint16_t* Pf = P_f16  + (size_t)bh * N_ * D_;
    const uint16_t* Pt = Pt_f16 + (size_t)bh * D_ * N_;

    // Q B-frag: B[k=d=c*32+quad*8+j][n=l15], row n0+l15; pre-scale by log2e
    f16x8 qf[2];
    {
        const uint16_t* qrow = Pf + (size_t)(n0 + l15) * D_ + quad * 8;
        qf[0] = ldf8(qrow); qf[1] = ldf8(qrow + 32);
        const _Float16 c = (_Float16)LOG2E;
        #pragma unroll
        for (int j = 0; j < 8; ++j) { qf[0][j] *= c; qf[1][j] *= c; }
    }

    // staging: thread covers slots tid, tid+256 of each 512-slot array.
    // LDS[row][c] = G[row][c ^ (row&7)]  (swizzle folded into global address)
    const int i0 = tid, i1 = tid + 256;
    const int r0s = i0 >> 3, c0s = i0 & 7;
    const int r1s = i1 >> 3, c1s = i1 & 7;
    const uint16_t* gK0 = Pf + (size_t)r0s * D_ + (c0s ^ (r0s & 7)) * 8;
    const uint16_t* gK1 = Pf + (size_t)r1s * D_ + (c1s ^ (r1s & 7)) * 8;
    const uint16_t* gV0 = Pt + (size_t)r0s * N_ + (c0s ^ (r0s & 7)) * 8;
    const uint16_t* gV1 = Pt + (size_t)r1s * N_ + (c1s ^ (r1s & 7)) * 8;

    // prologue: loads for tile 0
    int4 rK0 = *(const int4*)gK0, rK1 = *(const int4*)gK1;
    int4 rV0 = *(const int4*)gV0, rV1 = *(const int4*)gV1;

    float m_i = -1e30f, l_i = 0.0f;
    fx4 oacc[4];
    #pragma unroll
    for (int dt = 0; dt < 4; ++dt) oacc[dt] = (fx4)(0.0f);

    const int cc = quad ^ (l15 & 7);   // swizzled chunk for frag reads

    for (int it = 0; it < N_ / 64; ++it) {
        __syncthreads();
        ((int4*)sK)[i0] = rK0; ((int4*)sK)[i1] = rK1;
        ((int4*)sV)[i0] = rV0; ((int4*)sV)[i1] = rV1;
        const int knx = (it < N_ / 64 - 1) ? (it + 1) * 64 : 0;
        rK0 = *(const int4*)(gK0 + (size_t)knx * D_);
        rK1 = *(const int4*)(gK1 + (size_t)knx * D_);
        rV0 = *(const int4*)(gV0 + knx);
        rV1 = *(const int4*)(gV1 + knx);
        __syncthreads();

        // ---- S^T = K Q^T : lane holds keys {t*16+quad*4+r} of Q-row l15
        fx4 s[4];
        #pragma unroll
        for (int t = 0; t < 4; ++t) s[t] = (fx4)(0.0f);
        #pragma unroll
        for (int t = 0; t < 4; ++t) {
            const uint16_t* kb = sK + (t * 16 + l15) * 64;
            const f16x8 k0 = ldf8(kb + cc * 8);
            const f16x8 k1 = ldf8(kb + (cc ^ 4) * 8);
            s[t] = __builtin_amdgcn_mfma_f32_16x16x32_f16(k0, qf[0], s[t], 0, 0, 0);
            s[t] = __builtin_amdgcn_mfma_f32_16x16x32_f16(k1, qf[1], s[t], 0, 0, 0);
        }

        // ---- leakyrelu (scale-commutes) + online softmax in exp2 domain
        float pm[16];
        #pragma unroll
        for (int t = 0; t < 4; ++t)
            #pragma unroll
            for (int r = 0; r < 4; ++r) {
                const float v = s[t][r];
                pm[t * 4 + r] = fmaxf(v, NEG_SLOPE * v);
            }
        float mx = pm[0];
        #pragma unroll
        for (int j = 1; j < 16; ++j) mx = fmaxf(mx, pm[j]);
        mx = fmaxf(mx, __shfl_xor(mx, 16));
        mx = fmaxf(mx, __shfl_xor(mx, 32));
        const float mnew  = fmaxf(m_i, mx);
        const float alpha = __builtin_amdgcn_exp2f(m_i - mnew);
        float rs = 0.0f;
        #pragma unroll
        for (int j = 0; j < 16; ++j) {
            const float e = __builtin_amdgcn_exp2f(pm[j] - mnew);
            pm[j] = e; rs += e;
        }
        rs += __shfl_xor(rs, 16);
        rs += __shfl_xor(rs, 32);
        l_i = l_i * alpha + rs;
        m_i = mnew;
        #pragma unroll
        for (int dt = 0; dt < 4; ++dt)
            #pragma unroll
            for (int r = 0; r < 4; ++r) oacc[dt][r] *= alpha;

        // ---- probs (S^T layout) -> plds[row=l15][key] via packed b64 writes
        #pragma unroll
        for (int t = 0; t < 4; ++t) {
            const uint32_t w0 = pkh2(pm[t * 4 + 0], pm[t * 4 + 1]);
            const uint32_t w1 = pkh2(pm[t * 4 + 2], pm[t * 4 + 3]);
            uint2* dst = (uint2*)&plds[wave][l15][t * 16 + quad * 4];
            *dst = make_uint2(w0, w1);
        }
        // B-frag of probs: B[k=key=c*32+quad*8+j][n=l15]
        const f16x8 a0 = ldf8(&plds[wave][l15][quad * 8]);
        const f16x8 a1 = ldf8(&plds[wave][l15][32 + quad * 8]);

        // ---- O^T += V^T x P^T : A-frag from sV rows (d), B-frag = probs
        #pragma unroll
        for (int dt = 0; dt < 4; ++dt) {
            const uint16_t* vb = sV + (dt * 16 + l15) * 64;
            const f16x8 v0 = ldf8(vb + cc * 8);
            const f16x8 v1 = ldf8(vb + (cc ^ 4) * 8);
            oacc[dt] = __builtin_amdgcn_mfma_f32_16x16x32_f16(v0, a0, oacc[dt], 0, 0, 0);
            oacc[dt] = __builtin_amdgcn_mfma_f32_16x16x32_f16(v1, a1, oacc[dt], 0, 0, 0);
        }
    }

    // ---- epilogue: O^T layout: row(d) = dt*16+quad*4+r, col(Q-row) = l15
    const float inv = 1.0f / l_i;
    const size_t rowbase = ((size_t)b * N_ + n0 + l15) * FIN_ + hd * D_;
    #pragma unroll
    for (int dt = 0; dt < 4; ++dt)
        #pragma unroll
        for (int r = 0; r < 4; ++r) {
            const size_t idx = rowbase + dt * 16 + quad * 4 + r;
            out[idx] = oacc[dt][r] * inv + hin[idx];
        }
}

// ---------------------------------------------------------------------------
extern "C" void kernel_launch(void* const* d_in, const int* in_sizes, int n_in,
                              void* d_out, int out_size, void* d_ws, size_t ws_size,
                              hipStream_t stream) {
    const float* hin = (const float*)d_in[0];   // h   [8,2048,256] fp32
    // d_in[1] = adj — dead input
    const float* W   = (const float*)d_in[2];   // W   [4,256,64]   fp32
    float* out = (float*)d_out;

    // workspace (u16 elems): Wt_hi | Wt_lo | P_f16 | Pt_f16  (~17 MB)
    uint16_t* Wt_hi = (uint16_t*)d_ws;
    uint16_t* Wt_lo = Wt_hi + (size_t)H_ * D_ * FIN_;
    uint16_t* P_f16 = Wt_lo + (size_t)H_ * D_ * FIN_;
    uint16_t* Pt_f16= P_f16 + (size_t)B_ * H_ * N_ * D_;

    hipLaunchKernelGGL(prep_kernel, dim3(H_ * 16),         dim3(FIN_), 0, stream, W, Wt_hi, Wt_lo);
    hipLaunchKernelGGL(proj_kernel, dim3(N_/64, B_, H_/2), dim3(256),  0, stream,
                       hin, Wt_hi, Wt_lo, P_f16, Pt_f16);
    hipLaunchKernelGGL(attn_kernel, dim3(N_/64, B_*H_),    dim3(256),  0, stream,
                       P_f16, Pt_f16, hin, out);
}

// Round 7
// 252.963 us; speedup vs baseline: 2.1954x; 1.1002x over previous
//
#include <hip/hip_runtime.h>
#include <cstdint>

// Problem constants (MultiHeadGraphAttentionLayer_86638080295672)
#define B_    8
#define N_    2048
#define FIN_  256
#define H_    4
#define D_    64
#define NEG_SLOPE 0.2f
#define LOG2E 1.44269504f

typedef __bf16    bf16x8 __attribute__((ext_vector_type(8)));
typedef _Float16  f16x8  __attribute__((ext_vector_type(8)));
typedef uint16_t  u16x8  __attribute__((ext_vector_type(8)));
typedef float     fx4    __attribute__((ext_vector_type(4)));

static __device__ __forceinline__ float bf2f(uint16_t u) {
    union { uint32_t u; float f; } c; c.u = ((uint32_t)u) << 16; return c.f;
}
static __device__ __forceinline__ uint16_t f2bf(float f) {
    union { float f; uint32_t u; } c; c.f = f;
    return (uint16_t)((c.u + 0x7fffu + ((c.u >> 16) & 1u)) >> 16);  // RNE
}
static __device__ __forceinline__ uint16_t f2h(float f) {
    const _Float16 h = (_Float16)f;                 // v_cvt_f16_f32 RNE
    return __builtin_bit_cast(uint16_t, h);
}
static __device__ __forceinline__ bf16x8 ldbf8(const uint16_t* p) {
    return *(const bf16x8*)p;
}
static __device__ __forceinline__ f16x8 ldf8(const uint16_t* p) {
    return *(const f16x8*)p;
}
// pack two fp32 into one dword of bf16 (truncation; bias cancels in O/l ratio)
static __device__ __forceinline__ uint32_t pkbf_trunc(float lo, float hi) {
    const uint32_t ul = __builtin_bit_cast(uint32_t, lo);
    const uint32_t uh = __builtin_bit_cast(uint32_t, hi);
    return (ul >> 16) | (uh & 0xFFFF0000u);
}
// convert 8 contiguous fp32 -> f16x8 (RNE)
static __device__ __forceinline__ f16x8 cvt8(const float* p) {
    const float4 x0 = *(const float4*)p;
    const float4 x1 = *(const float4*)(p + 4);
    const float f[8] = {x0.x, x0.y, x0.z, x0.w, x1.x, x1.y, x1.z, x1.w};
    f16x8 r;
    #pragma unroll
    for (int j = 0; j < 8; ++j) r[j] = (_Float16)f[j];
    return r;
}

// ---------------------------------------------------------------------------
// Kernel 0 (prep): Wt_f16[h][d][f] = (fp16) W[h][f][d]
// ---------------------------------------------------------------------------
__global__ void prep_kernel(const float* __restrict__ W,
                            uint16_t* __restrict__ Wt_f16) {
    const int h  = blockIdx.x >> 4;
    const int d4 = blockIdx.x & 15;
    const int f  = threadIdx.x;
    const float4 w = *(const float4*)(W + (((size_t)h * FIN_ + f) * D_ + d4 * 4));
    const float vv[4] = {w.x, w.y, w.z, w.w};
    #pragma unroll
    for (int j = 0; j < 4; ++j) {
        const int d = d4 * 4 + j;
        Wt_f16[((size_t)h * D_ + d) * FIN_ + f] = f2h(vv[j]);
    }
}

// ---------------------------------------------------------------------------
// Kernel 1: P = h @ W, single-product fp16 MFMA. Writes P_f16 [BH][N][D]
// (Q/K source) and Pt_bf16 [BH][D][N] (V source for the bf16 PV MFMA).
// ---------------------------------------------------------------------------
__global__ __launch_bounds__(256, 2) void proj_kernel(
    const float*    __restrict__ hin,
    const uint16_t* __restrict__ Wt_f16,
    uint16_t* __restrict__ P_f16,
    uint16_t* __restrict__ Pt_bf16)
{
    __shared__ __align__(16) uint16_t plds[4][16][72];

    const int lane = threadIdx.x & 63, wave = threadIdx.x >> 6;
    const int quad = lane >> 4, l15 = lane & 15;

    const int b  = blockIdx.y;
    const int h0 = blockIdx.z * 2;
    const int n0 = blockIdx.x * 64 + wave * 16;

    const float* arow = hin + ((size_t)b * N_ + n0 + l15) * FIN_ + quad * 8;

    fx4 acc[2][4];
    #pragma unroll
    for (int hh = 0; hh < 2; ++hh)
        #pragma unroll
        for (int t = 0; t < 4; ++t) acc[hh][t] = (fx4)(0.0f);

    #pragma unroll
    for (int k0 = 0; k0 < FIN_; k0 += 32) {
        const f16x8 a = cvt8(arow + k0);   // A[m=l15][k=quad*8+j]
        #pragma unroll
        for (int hh = 0; hh < 2; ++hh) {
            const uint16_t* wb = Wt_f16 + (size_t)(h0 + hh) * D_ * FIN_;
            #pragma unroll
            for (int t = 0; t < 4; ++t) {
                const f16x8 bb = ldf8(wb + (size_t)(t * 16 + l15) * FIN_ + k0 + quad * 8);
                acc[hh][t] = __builtin_amdgcn_mfma_f32_16x16x32_f16(a, bb, acc[hh][t], 0, 0, 0);
            }
        }
    }

    #pragma unroll
    for (int hh = 0; hh < 2; ++hh) {
        const int bh = b * H_ + h0 + hh;
        // pass 1: fp16 -> plds -> row-contiguous P_f16 (b128 stores)
        #pragma unroll
        for (int t = 0; t < 4; ++t)
            #pragma unroll
            for (int r = 0; r < 4; ++r)
                plds[wave][quad * 4 + r][t * 16 + l15] = f2h(acc[hh][t][r]);
        {
            const uint16_t* base = &plds[wave][l15][0];
            const int4 r0 = *(const int4*)(base + quad * 8);
            const int4 r1 = *(const int4*)(base + quad * 8 + 32);
            uint16_t* pg = P_f16 + ((size_t)bh * N_ + n0 + l15) * D_;
            *(int4*)(pg + quad * 8)      = r0;
            *(int4*)(pg + quad * 8 + 32) = r1;
        }
        // pass 2: bf16 -> plds -> transposed Pt_bf16 (b128 stores, lane = d)
        #pragma unroll
        for (int t = 0; t < 4; ++t)
            #pragma unroll
            for (int r = 0; r < 4; ++r)
                plds[wave][quad * 4 + r][t * 16 + l15] = f2bf(acc[hh][t][r]);
        {
            uint32_t u[8];
            #pragma unroll
            for (int j = 0; j < 8; ++j) {
                const uint16_t e0 = plds[wave][2 * j][lane];
                const uint16_t e1 = plds[wave][2 * j + 1][lane];
                u[j] = (uint32_t)e0 | ((uint32_t)e1 << 16);
            }
            uint16_t* pt = Pt_bf16 + ((size_t)bh * D_ + lane) * N_ + n0;
            int4 s0, s1;
            s0.x = u[0]; s0.y = u[1]; s0.z = u[2]; s0.w = u[3];
            s1.x = u[4]; s1.y = u[5]; s1.z = u[6]; s1.w = u[7];
            *(int4*)pt       = s0;
            *(int4*)(pt + 8) = s1;
        }
    }
}

// ---------------------------------------------------------------------------
// Kernel 2: flash attention, S^T formulation, no per-iter max. Probs are
// exp2(lrelu(s)*log2e - C_i) with the a-priori per-row shift C_i = diag
// score s_ii = |q_i|^2 (self-attention: any consistent per-row constant is
// exact for softmax; diag bounds the row max to within |q||M|-|q|^2 <~ 43
// exp2-units << 127, and guarantees denom >= 1). Denominator via ones-MFMA.
// 4 waves x 32 Q-rows = 128 rows/block; double-buffered K/V staging.
// ---------------------------------------------------------------------------
__global__ __launch_bounds__(256, 2) void attn_kernel(
    const uint16_t* __restrict__ P_f16,    // [BH][N][D] fp16 (Q,K)
    const uint16_t* __restrict__ Pt_bf16,  // [BH][D][N] bf16 (V)
    const float*    __restrict__ hin,
    float*          __restrict__ out)
{
    __shared__ __align__(16) uint16_t sK[2][64 * 64];
    __shared__ __align__(16) uint16_t sV[2][64 * 64];
    __shared__ __align__(16) uint16_t plds[4][32][72];

    const int tid  = threadIdx.x;
    const int lane = tid & 63, wave = tid >> 6;
    const int quad = lane >> 4, l15 = lane & 15;

    const int bh = blockIdx.y, b = bh >> 2, hd = bh & 3;
    const int n0 = blockIdx.x * 128 + wave * 32;

    const uint16_t* Pf = P_f16   + (size_t)bh * N_ * D_;
    const uint16_t* Pt = Pt_bf16 + (size_t)bh * D_ * N_;

    // Q B-frags, 2 m-tiles, pre-scaled by log2e (exp -> exp2; lrelu commutes)
    f16x8 qf[2][2];
    #pragma unroll
    for (int mt = 0; mt < 2; ++mt) {
        const uint16_t* qrow = Pf + (size_t)(n0 + mt * 16 + l15) * D_ + quad * 8;
        qf[mt][0] = ldf8(qrow); qf[mt][1] = ldf8(qrow + 32);
        const _Float16 c = (_Float16)LOG2E;
        #pragma unroll
        for (int j = 0; j < 8; ++j) { qf[mt][0][j] *= c; qf[mt][1][j] *= c; }
    }

    // per-row shift C[mt] = s_diag * log2e = |qhat|^2 / log2e
    // (lane holds 16 of 64 elems of its Q-row; sum across the 4 quads)
    float C[2];
    #pragma unroll
    for (int mt = 0; mt < 2; ++mt) {
        float acc = 0.0f;
        #pragma unroll
        for (int j = 0; j < 8; ++j) {
            const float a0 = (float)qf[mt][0][j], a1 = (float)qf[mt][1][j];
            acc += a0 * a0 + a1 * a1;
        }
        acc += __shfl_xor(acc, 16);
        acc += __shfl_xor(acc, 32);
        C[mt] = acc * (1.0f / LOG2E);
    }

    // all-ones bf16 A-frag for the denominator MFMA
    bf16x8 ones;
    {
        u16x8 ov;
        #pragma unroll
        for (int j = 0; j < 8; ++j) ov[j] = 0x3F80;
        ones = __builtin_bit_cast(bf16x8, ov);
    }

    // staging: thread covers slots tid, tid+256 of each 512-slot buffer.
    // LDS[row][c] = G[row][c ^ (row&7)] (swizzle folded into global address)
    const int i0 = tid, i1 = tid + 256;
    const int r0s = i0 >> 3, c0s = i0 & 7;
    const int r1s = i1 >> 3, c1s = i1 & 7;
    const uint16_t* gK0 = Pf + (size_t)r0s * D_ + (c0s ^ (r0s & 7)) * 8;
    const uint16_t* gK1 = Pf + (size_t)r1s * D_ + (c1s ^ (r1s & 7)) * 8;
    const uint16_t* gV0 = Pt + (size_t)r0s * N_ + (c0s ^ (r0s & 7)) * 8;
    const uint16_t* gV1 = Pt + (size_t)r1s * N_ + (c1s ^ (r1s & 7)) * 8;

    // prologue: tile 0 -> buf 0; tile 1 -> regs
    {
        int4 a = *(const int4*)gK0, bb = *(const int4*)gK1;
        int4 c = *(const int4*)gV0, d  = *(const int4*)gV1;
        ((int4*)sK[0])[i0] = a;  ((int4*)sK[0])[i1] = bb;
        ((int4*)sV[0])[i0] = c;  ((int4*)sV[0])[i1] = d;
    }
    int4 rK0 = *(const int4*)(gK0 + (size_t)64 * D_);
    int4 rK1 = *(const int4*)(gK1 + (size_t)64 * D_);
    int4 rV0 = *(const int4*)(gV0 + 64);
    int4 rV1 = *(const int4*)(gV1 + 64);

    fx4 oacc[2][4], lacc[2];
    #pragma unroll
    for (int mt = 0; mt < 2; ++mt) {
        lacc[mt] = (fx4)(0.0f);
        #pragma unroll
        for (int dt = 0; dt < 4; ++dt) oacc[mt][dt] = (fx4)(0.0f);
    }

    const int cc = quad ^ (l15 & 7);   // swizzled chunk for frag reads

    __syncthreads();
    for (int it = 0; it < N_ / 64; ++it) {
        const int cur = it & 1;
        // write tile it+1 (in regs) into the other buffer
        if (it < N_ / 64 - 1) {
            ((int4*)sK[cur ^ 1])[i0] = rK0; ((int4*)sK[cur ^ 1])[i1] = rK1;
            ((int4*)sV[cur ^ 1])[i0] = rV0; ((int4*)sV[cur ^ 1])[i1] = rV1;
        }
        // prefetch tile it+2 into regs
        if (it < N_ / 64 - 2) {
            const size_t ko = (size_t)(it + 2) * 64;
            rK0 = *(const int4*)(gK0 + ko * D_);
            rK1 = *(const int4*)(gK1 + ko * D_);
            rV0 = *(const int4*)(gV0 + ko);
            rV1 = *(const int4*)(gV1 + ko);
        }

        // ---- S^T = K Q^T : lane holds keys {t*16+quad*4+r} of its Q-rows
        fx4 s[2][4];
        #pragma unroll
        for (int mt = 0; mt < 2; ++mt)
            #pragma unroll
            for (int t = 0; t < 4; ++t) s[mt][t] = (fx4)(0.0f);
        #pragma unroll
        for (int t = 0; t < 4; ++t) {
            const uint16_t* kb = &sK[cur][(t * 16 + l15) * 64];
            const f16x8 k0 = ldf8(kb + cc * 8);
            const f16x8 k1 = ldf8(kb + (cc ^ 4) * 8);
            #pragma unroll
            for (int mt = 0; mt < 2; ++mt) {
                s[mt][t] = __builtin_amdgcn_mfma_f32_16x16x32_f16(k0, qf[mt][0], s[mt][t], 0, 0, 0);
                s[mt][t] = __builtin_amdgcn_mfma_f32_16x16x32_f16(k1, qf[mt][1], s[mt][t], 0, 0, 0);
            }
        }

        // ---- probs = exp2(lrelu(s)*log2e - C) ; pack bf16 -> plds
        #pragma unroll
        for (int mt = 0; mt < 2; ++mt) {
            #pragma unroll
            for (int t = 0; t < 4; ++t) {
                float e[4];
                #pragma unroll
                for (int r = 0; r < 4; ++r) {
                    const float v = s[mt][t][r];
                    e[r] = __builtin_amdgcn_exp2f(fmaxf(v, NEG_SLOPE * v) - C[mt]);
                }
                const uint32_t w0 = pkbf_trunc(e[0], e[1]);
                const uint32_t w1 = pkbf_trunc(e[2], e[3]);
                *(uint2*)&plds[wave][mt * 16 + l15][t * 16 + quad * 4] = make_uint2(w0, w1);
            }
        }

        // B-frags of probs: B[k=key=c*32+quad*8+j][n=qrow=l15]
        bf16x8 a[2][2];
        #pragma unroll
        for (int mt = 0; mt < 2; ++mt) {
            const uint16_t* pb = &plds[wave][mt * 16 + l15][0];
            a[mt][0] = ldbf8(pb + quad * 8);
            a[mt][1] = ldbf8(pb + quad * 8 + 32);
        }

        // ---- denominator: lacc[m][n=qrow] += sum_k probs  (matrix pipe)
        #pragma unroll
        for (int mt = 0; mt < 2; ++mt) {
            lacc[mt] = __builtin_amdgcn_mfma_f32_16x16x32_bf16(ones, a[mt][0], lacc[mt], 0, 0, 0);
            lacc[mt] = __builtin_amdgcn_mfma_f32_16x16x32_bf16(ones, a[mt][1], lacc[mt], 0, 0, 0);
        }
        // ---- O^T += V^T x P^T
        #pragma unroll
        for (int dt = 0; dt < 4; ++dt) {
            const uint16_t* vb = &sV[cur][(dt * 16 + l15) * 64];
            const bf16x8 v0 = ldbf8(vb + cc * 8);
            const bf16x8 v1 = ldbf8(vb + (cc ^ 4) * 8);
            #pragma unroll
            for (int mt = 0; mt < 2; ++mt) {
                oacc[mt][dt] = __builtin_amdgcn_mfma_f32_16x16x32_bf16(v0, a[mt][0], oacc[mt][dt], 0, 0, 0);
                oacc[mt][dt] = __builtin_amdgcn_mfma_f32_16x16x32_bf16(v1, a[mt][1], oacc[mt][dt], 0, 0, 0);
            }
        }
        __syncthreads();
    }

    // ---- epilogue: O^T layout row(d)=dt*16+quad*4+r, col(qrow)=l15.
    // lacc rows are all identical = l(qrow=l15): no cross-lane reduce needed.
    #pragma unroll
    for (int mt = 0; mt < 2; ++mt) {
        const float inv = 1.0f / lacc[mt][0];
        const size_t rowbase = ((size_t)b * N_ + n0 + mt * 16 + l15) * FIN_ + hd * D_;
        #pragma unroll
        for (int dt = 0; dt < 4; ++dt) {
            const size_t idx = rowbase + dt * 16 + quad * 4;
            const float4 hv = *(const float4*)&hin[idx];
            float4 o;
            o.x = oacc[mt][dt][0] * inv + hv.x;
            o.y = oacc[mt][dt][1] * inv + hv.y;
            o.z = oacc[mt][dt][2] * inv + hv.z;
            o.w = oacc[mt][dt][3] * inv + hv.w;
            *(float4*)&out[idx] = o;
        }
    }
}

// ---------------------------------------------------------------------------
extern "C" void kernel_launch(void* const* d_in, const int* in_sizes, int n_in,
                              void* d_out, int out_size, void* d_ws, size_t ws_size,
                              hipStream_t stream) {
    const float* hin = (const float*)d_in[0];   // h   [8,2048,256] fp32
    // d_in[1] = adj — dead input (never used by the reference math)
    const float* W   = (const float*)d_in[2];   // W   [4,256,64]   fp32
    float* out = (float*)d_out;

    // workspace (u16 elems): Wt_f16 | P_f16 | Pt_bf16  (~17 MB)
    uint16_t* Wt_f16  = (uint16_t*)d_ws;
    uint16_t* P_f16   = Wt_f16 + (size_t)H_ * D_ * FIN_;
    uint16_t* Pt_bf16 = P_f16  + (size_t)B_ * H_ * N_ * D_;

    hipLaunchKernelGGL(prep_kernel, dim3(H_ * 16),         dim3(FIN_), 0, stream, W, Wt_f16);
    hipLaunchKernelGGL(proj_kernel, dim3(N_/64, B_, H_/2), dim3(256),  0, stream,
                       hin, Wt_f16, P_f16, Pt_bf16);
    hipLaunchKernelGGL(attn_kernel, dim3(N_/128, B_*H_),   dim3(256),  0, stream,
                       P_f16, Pt_bf16, hin, out);
}